// Round 3
// baseline (548.606 us; speedup 1.0000x reference)
//
#include <hip/hip_runtime.h>

#define IMG_H 512
#define IMG_W 512
#define CH_STRIDE (IMG_H*IMG_W)     // 262144
#define IMG_STRIDE (3*CH_STRIDE)

using f4 = __attribute__((ext_vector_type(4))) float;
using h4 = __attribute__((ext_vector_type(4))) _Float16;

// ws accumulators: 0=con 1=gx 2=gy 3=cb 4=cr 5=ssim_rgb 6=ssim_ir
__global__ __launch_bounds__(64) void k_zero(float* acc) {
  if (threadIdx.x < 8) acc[threadIdx.x] = 0.f;
}

// ---------------- block reduction helper (256 threads = 4 waves) ----------
__device__ __forceinline__ float block_sum(float v, float* red) {
  #pragma unroll
  for (int o = 32; o > 0; o >>= 1) v += __shfl_down(v, o, 64);
  __syncthreads();
  if ((threadIdx.x & 63) == 0) red[threadIdx.x >> 6] = v;
  __syncthreads();
  return red[0] + red[1] + red[2] + red[3];
}

// ---------------- kernel 1: con + sobel-gradient + color partials ---------
// Tile 64x16, halo 1. Stage ONE channel (vis,ir,fuse) at a time: 14.7 KB LDS
// -> ~7 blocks/CU (vs 3 at R2's 44.5 KB). 6 barriers/block, overlapped.
#define T1W 64
#define T1H 16
#define R1W 68        // 66 valid cols, 2 pad (16B-aligned rows)
#define R1H 18
#define R1N (R1W*R1H) // 1224

__global__ __launch_bounds__(256) void k_point_sobel(
    const float* __restrict__ vis, const float* __restrict__ ir,
    const float* __restrict__ fuse, float* __restrict__ acc)
{
  __shared__ __align__(16) float s[3*R1N];
  __shared__ float red[4];
  const int tid = threadIdx.x;
  const int n  = blockIdx.z;
  const int x0 = blockIdx.x * T1W;
  const int y0 = blockIdx.y * T1H;
  const int ox = (tid & 15) * 4;     // 0..60
  const int oy = tid >> 4;           // 0..15

  float con=0.f, gxs=0.f, gys=0.f, cbs=0.f, crs=0.f;
  float pv[3][4], pf[3][4];

  for (int c = 0; c < 3; ++c) {
    // stage vis/ir/fuse channel c (zero-padded halo)
    for (int i = tid; i < 3*R1N; i += 256) {
      int f  = i / R1N;
      int r  = i - f*R1N;
      int ly = r / R1W, lx = r - ly*R1W;
      int gy = y0 - 1 + ly, gx = x0 - 1 + lx;
      float v = 0.f;
      const float* bp = (f == 0) ? vis : ((f == 1) ? ir : fuse);
      if (lx < 66 && (unsigned)gx < IMG_W && (unsigned)gy < IMG_H)
        v = bp[(n*3 + c)*CH_STRIDE + gy*IMG_W + gx];
      s[i] = v;
    }
    __syncthreads();

    float cen[3][4], gxv[3][4], gyv[3][4];
    #pragma unroll
    for (int t = 0; t < 3; ++t) {
      const float* sf = s + t*R1N;
      float r0[8], r1[8], r2[8];
      {
        f4 a = *(const f4*)&sf[(oy+0)*R1W + ox], b = *(const f4*)&sf[(oy+0)*R1W + ox + 4];
        r0[0]=a.x; r0[1]=a.y; r0[2]=a.z; r0[3]=a.w; r0[4]=b.x; r0[5]=b.y; r0[6]=b.z; r0[7]=b.w;
      }
      {
        f4 a = *(const f4*)&sf[(oy+1)*R1W + ox], b = *(const f4*)&sf[(oy+1)*R1W + ox + 4];
        r1[0]=a.x; r1[1]=a.y; r1[2]=a.z; r1[3]=a.w; r1[4]=b.x; r1[5]=b.y; r1[6]=b.z; r1[7]=b.w;
      }
      {
        f4 a = *(const f4*)&sf[(oy+2)*R1W + ox], b = *(const f4*)&sf[(oy+2)*R1W + ox + 4];
        r2[0]=a.x; r2[1]=a.y; r2[2]=a.z; r2[3]=a.w; r2[4]=b.x; r2[5]=b.y; r2[6]=b.z; r2[7]=b.w;
      }
      #pragma unroll
      for (int j = 0; j < 4; ++j) {
        gxv[t][j] = (r0[j+2]-r0[j]) + 2.f*(r1[j+2]-r1[j]) + (r2[j+2]-r2[j]);
        gyv[t][j] = (r0[j] + 2.f*r0[j+1] + r0[j+2]) - (r2[j] + 2.f*r2[j+1] + r2[j+2]);
        cen[t][j] = r1[j+1];
      }
    }
    #pragma unroll
    for (int j = 0; j < 4; ++j) {
      con += fabsf(cen[2][j] - fmaxf(cen[0][j], cen[1][j]));
      gxs += fabsf(gxv[2][j] - fmaxf(gxv[0][j], gxv[1][j]));
      gys += fabsf(gyv[2][j] - fmaxf(gyv[0][j], gyv[1][j]));
      pv[c][j] = cen[0][j];
      pf[c][j] = cen[2][j];
    }
    __syncthreads();   // WAR guard before restaging (and before block_sum reuse)
  }

  #pragma unroll
  for (int j = 0; j < 4; ++j) {
    float Yf = 0.299f*pf[0][j] + 0.587f*pf[1][j] + 0.114f*pf[2][j];
    float Yv = 0.299f*pv[0][j] + 0.587f*pv[1][j] + 0.114f*pv[2][j];
    crs += fabsf(0.713f*((pf[0][j]-Yf) - (pv[0][j]-Yv)));
    cbs += fabsf(0.564f*((pf[2][j]-Yf) - (pv[2][j]-Yv)));
  }

  float r0 = block_sum(con, red);
  float r1 = block_sum(gxs, red);
  float r2 = block_sum(gys, red);
  float r3 = block_sum(cbs, red);
  float r4 = block_sum(crs, red);
  if (tid == 0) {
    atomicAdd(&acc[0], r0);
    atomicAdd(&acc[1], r1);
    atomicAdd(&acc[2], r2);
    atomicAdd(&acc[3], r3);
    atomicAdd(&acc[4], r4);
  }
}

// ---------------- kernel 2: SSIM partials (one (n,pair) per blockIdx.z) ---
// Tile 64x32, halo 5. f16 staging + f16 hbuf: 35.6 KB LDS -> 4 blocks/CU.
#define T2W 64
#define T2H 32
#define SXW 76        // halves/row, 74 valid + 2 pad (8B-aligned 4-groups)
#define SXH 42
#define HBW 68        // halves/row, 64 valid + 4 pad
#define SXN (SXH*SXW) // 3192
#define HBN (SXH*HBW) // 2856

__global__ __launch_bounds__(256) void k_ssim(
    const float* __restrict__ vis, const float* __restrict__ ir,
    const float* __restrict__ fuse, float* __restrict__ acc)
{
  __shared__ __align__(16) _Float16 sx[SXN];
  __shared__ __align__(16) _Float16 sy[SXN];
  __shared__ __align__(16) _Float16 hA[HBN];
  __shared__ __align__(16) _Float16 hB[HBN];
  __shared__ __align__(16) _Float16 hP[HBN];
  __shared__ __align__(16) _Float16 hQ[HBN];
  __shared__ float red[4];
  const int tid = threadIdx.x;
  const int z = blockIdx.z;            // n*4 + pair
  const int n = z >> 2, pair = z & 3;
  const int x0 = blockIdx.x*T2W;
  const int y0 = blockIdx.y*T2H;

  // Gaussian weights (fp64-accurate unnormalized exp(-d^2/4.5), normalized)
  float g[11];
  {
    const float gu[6] = {0.00386592014f, 0.02856550078f, 0.13533528324f,
                         0.41111229050f, 0.80073740292f, 1.0f};
    float gs = 0.f;
    #pragma unroll
    for (int i = 0; i < 11; ++i) { g[i] = gu[i < 6 ? i : 10 - i]; gs += g[i]; }
    #pragma unroll
    for (int i = 0; i < 11; ++i) g[i] /= gs;
  }

  // stage (zero-padded) as f16
  if (pair < 3) {
    const float* xb = vis  + (n*3 + pair)*CH_STRIDE;
    const float* yb = fuse + (n*3 + pair)*CH_STRIDE;
    for (int i = tid; i < SXN; i += 256) {
      int ly = i / SXW, lx = i - ly*SXW;
      int gy = y0 - 5 + ly, gx = x0 - 5 + lx;
      float xa = 0.f, ya = 0.f;
      if (lx < 74 && (unsigned)gx < IMG_W && (unsigned)gy < IMG_H) {
        int off = gy*IMG_W + gx;
        xa = xb[off]; ya = yb[off];
      }
      sx[i] = (_Float16)xa; sy[i] = (_Float16)ya;
    }
  } else {
    const float* xb = ir   + n*IMG_STRIDE;
    const float* fb = fuse + n*IMG_STRIDE;
    for (int i = tid; i < SXN; i += 256) {
      int ly = i / SXW, lx = i - ly*SXW;
      int gy = y0 - 5 + ly, gx = x0 - 5 + lx;
      float xa = 0.f, ya = 0.f;
      if (lx < 74 && (unsigned)gx < IMG_W && (unsigned)gy < IMG_H) {
        int off = gy*IMG_W + gx;
        xa = xb[off];
        ya = 0.2989f*fb[off] + 0.587f*fb[off + CH_STRIDE] + 0.114f*fb[off + 2*CH_STRIDE];
      }
      sx[i] = (_Float16)xa; sy[i] = (_Float16)ya;
    }
  }
  __syncthreads();

  // horizontal pass: 672 groups (42 rows x 16 xgroups), 4-wide outputs
  for (int gi = tid; gi < SXH*16; gi += 256) {
    int row = gi >> 4, gox = (gi & 15) * 4;
    int base = row*SXW + gox;
    float wa[16], wb[16], wp[14], wq[14];
    #pragma unroll
    for (int u = 0; u < 4; ++u) {
      h4 av = *(const h4*)&sx[base + 4*u];
      h4 bv = *(const h4*)&sy[base + 4*u];
      #pragma unroll
      for (int j = 0; j < 4; ++j) { wa[4*u+j] = (float)av[j]; wb[4*u+j] = (float)bv[j]; }
    }
    #pragma unroll
    for (int i = 0; i < 14; ++i) {
      wp[i] = fmaf(wa[i], wa[i], wb[i]*wb[i]);
      wq[i] = wa[i]*wb[i];
    }
    float hA4[4]={0,0,0,0}, hB4[4]={0,0,0,0}, hP4[4]={0,0,0,0}, hQ4[4]={0,0,0,0};
    #pragma unroll
    for (int k = 0; k < 11; ++k) {
      float gk = g[k];
      #pragma unroll
      for (int j = 0; j < 4; ++j) {
        hA4[j] = fmaf(gk, wa[k+j], hA4[j]);
        hB4[j] = fmaf(gk, wb[k+j], hB4[j]);
        hP4[j] = fmaf(gk, wp[k+j], hP4[j]);
        hQ4[j] = fmaf(gk, wq[k+j], hQ4[j]);
      }
    }
    int ob = row*HBW + gox;
    *(h4*)&hA[ob] = h4{(_Float16)hA4[0], (_Float16)hA4[1], (_Float16)hA4[2], (_Float16)hA4[3]};
    *(h4*)&hB[ob] = h4{(_Float16)hB4[0], (_Float16)hB4[1], (_Float16)hB4[2], (_Float16)hB4[3]};
    *(h4*)&hP[ob] = h4{(_Float16)hP4[0], (_Float16)hP4[1], (_Float16)hP4[2], (_Float16)hP4[3]};
    *(h4*)&hQ[ob] = h4{(_Float16)hQ4[0], (_Float16)hQ4[1], (_Float16)hQ4[2], (_Float16)hQ4[3]};
  }
  __syncthreads();

  // vertical pass: 256 strips of 4 wide x 2 rows, streaming 12 hbuf rows
  const int vox = (tid & 15) * 4;
  const int yb2 = (tid >> 4) * 2;    // 0,2,..,30
  float aA0[4]={0,0,0,0}, aA1[4]={0,0,0,0};
  float aB0[4]={0,0,0,0}, aB1[4]={0,0,0,0};
  float aP0[4]={0,0,0,0}, aP1[4]={0,0,0,0};
  float aQ0[4]={0,0,0,0}, aQ1[4]={0,0,0,0};
  #pragma unroll
  for (int r = 0; r < 12; ++r) {
    int rb = (yb2 + r)*HBW + vox;
    h4 fA = *(const h4*)&hA[rb];
    h4 fB = *(const h4*)&hB[rb];
    h4 fP = *(const h4*)&hP[rb];
    h4 fQ = *(const h4*)&hQ[rb];
    if (r < 11) {
      float gk = g[r];
      #pragma unroll
      for (int j = 0; j < 4; ++j) {
        aA0[j] = fmaf(gk, (float)fA[j], aA0[j]);
        aB0[j] = fmaf(gk, (float)fB[j], aB0[j]);
        aP0[j] = fmaf(gk, (float)fP[j], aP0[j]);
        aQ0[j] = fmaf(gk, (float)fQ[j], aQ0[j]);
      }
    }
    if (r >= 1) {
      float gk = g[r-1];
      #pragma unroll
      for (int j = 0; j < 4; ++j) {
        aA1[j] = fmaf(gk, (float)fA[j], aA1[j]);
        aB1[j] = fmaf(gk, (float)fB[j], aB1[j]);
        aP1[j] = fmaf(gk, (float)fP[j], aP1[j]);
        aQ1[j] = fmaf(gk, (float)fQ[j], aQ1[j]);
      }
    }
  }

  float ss = 0.f;
  #pragma unroll
  for (int j = 0; j < 4; ++j) {
    {
      float mu1 = aA0[j], mu2 = aB0[j];
      float mu12 = mu1*mu2, mss = mu1*mu1 + mu2*mu2;
      float s12 = aQ0[j] - mu12, sps = aP0[j] - mss;
      ss += ((2.f*mu12 + 1e-4f)*(2.f*s12 + 9e-4f)) / ((mss + 1e-4f)*(sps + 9e-4f));
    }
    {
      float mu1 = aA1[j], mu2 = aB1[j];
      float mu12 = mu1*mu2, mss = mu1*mu1 + mu2*mu2;
      float s12 = aQ1[j] - mu12, sps = aP1[j] - mss;
      ss += ((2.f*mu12 + 1e-4f)*(2.f*s12 + 9e-4f)) / ((mss + 1e-4f)*(sps + 9e-4f));
    }
  }
  float tot = block_sum(ss, red);
  if (tid == 0) atomicAdd(&acc[(pair == 3) ? 6 : 5], tot);
}

// ---------------- kernel 3: final combine (reads 7 scalars) ---------------
__global__ __launch_bounds__(64) void k_final(
    const float* __restrict__ acc, float* __restrict__ out)
{
  if (threadIdx.x == 0) {
    const float N3 = 16.f*3.f*512.f*512.f;
    const float N1 = 16.f*512.f*512.f;
    float con_loss  = acc[0] / N3;
    float grad_loss = 0.5f*(acc[1]/N3) + 0.5f*(acc[2]/N3);
    float color_loss = acc[3]/N1 + acc[4]/N1;
    float ssim_loss = 1.f - (acc[5]/N3 + acc[6]/N1)*0.5f;
    out[0] = 0.5f*con_loss + 0.2f*grad_loss + color_loss + 0.1f*ssim_loss;
  }
}

extern "C" void kernel_launch(void* const* d_in, const int* in_sizes, int n_in,
                              void* d_out, int out_size, void* d_ws, size_t ws_size,
                              hipStream_t stream) {
  (void)in_sizes; (void)n_in; (void)out_size; (void)ws_size;
  const float* vis  = (const float*)d_in[0];
  const float* ir   = (const float*)d_in[1];
  const float* fuse = (const float*)d_in[2];
  float* out = (float*)d_out;
  float* acc = (float*)d_ws;   // 8 floats, zeroed then atomically accumulated

  k_zero<<<dim3(1,1,1), dim3(64,1,1), 0, stream>>>(acc);
  dim3 b(256,1,1);
  k_point_sobel<<<dim3(8, 32, 16), b, 0, stream>>>(vis, ir, fuse, acc);
  k_ssim<<<dim3(8, 16, 64), b, 0, stream>>>(vis, ir, fuse, acc);
  k_final<<<dim3(1,1,1), dim3(64,1,1), 0, stream>>>(acc, out);
}

// Round 4
// 255.401 us; speedup vs baseline: 2.1480x; 2.1480x over previous
//
#include <hip/hip_runtime.h>

#define IMG_H 512
#define IMG_W 512
#define CH_STRIDE (IMG_H*IMG_W)     // 262144
#define IMG_STRIDE (3*CH_STRIDE)

using f4 = __attribute__((ext_vector_type(4))) float;
using h4 = __attribute__((ext_vector_type(4))) _Float16;

// acc: 64 slots x 32 floats (128 B apart). counters within slot:
// 0=con 1=gx 2=gy 3=cb 4=cr 5=ssim_rgb 6=ssim_ir
#define NSLOT 64
#define SLOT_F 32

__global__ __launch_bounds__(256) void k_zero(float* __restrict__ acc) {
  int i = threadIdx.x;
  *(f4*)&acc[i*8]     = f4{0,0,0,0};
  *(f4*)&acc[i*8 + 4] = f4{0,0,0,0};
}

// ---------------- block reduction helper (256 threads = 4 waves) ----------
__device__ __forceinline__ float block_sum(float v, float* red) {
  #pragma unroll
  for (int o = 32; o > 0; o >>= 1) v += __shfl_down(v, o, 64);
  __syncthreads();
  if ((threadIdx.x & 63) == 0) red[threadIdx.x >> 6] = v;
  __syncthreads();
  return red[0] + red[1] + red[2] + red[3];
}

// ---- k1 geometry: tile 64x16, halo 1; LDS row stride 68 floats ----------
#define R1W 68
#define R1N (18*R1W)   // 1224 floats per field

// ---- ssim geometry: tile 64x32, halo 5; staged rows 42 x 80 halves ------
// element at image x = x0-8+u  <->  LDS idx u (u=0..79); valid data u=3..76
#define SXW 80
#define SXH 42
#define HBW 68          // hbuf halves/row: 64 valid + 4 pad
#define HBN (SXH*HBW)   // 2856

#define SMEM_BYTES 36288  // ssim: sx 6720 | sy 6720 | hA/hB/hP/hQ 4*5712

__global__ __launch_bounds__(256, 4) void k_main(
    const float* __restrict__ vis, const float* __restrict__ ir,
    const float* __restrict__ fuse, float* __restrict__ acc)
{
  __shared__ __align__(16) char smem[SMEM_BYTES];
  __shared__ float red[4];
  const int tid = threadIdx.x;
  const int bid = blockIdx.x;
  float* aslot = acc + (bid & (NSLOT-1))*SLOT_F;

  if (bid < 8192) {
    // ================= SSIM block =================
    const int z = bid >> 7;             // n*4 + pair
    const int n = z >> 2, pair = z & 3;
    const int x0 = (bid & 7)*64;
    const int y0 = ((bid >> 3) & 15)*32;
    _Float16* sx = (_Float16*)smem;
    _Float16* sy = (_Float16*)(smem + 6720);
    _Float16* hA = (_Float16*)(smem + 13440);
    _Float16* hB = (_Float16*)(smem + 19152);
    _Float16* hP = (_Float16*)(smem + 24864);
    _Float16* hQ = (_Float16*)(smem + 30576);

    // Gaussian weights (fp64-accurate unnormalized exp(-d^2/4.5), normalized)
    float g[11];
    {
      const float gu[6] = {0.00386592014f, 0.02856550078f, 0.13533528324f,
                           0.41111229050f, 0.80073740292f, 1.0f};
      float gs = 0.f;
      #pragma unroll
      for (int i = 0; i < 11; ++i) { g[i] = gu[i < 6 ? i : 10 - i]; gs += g[i]; }
      #pragma unroll
      for (int i = 0; i < 11; ++i) g[i] /= gs;
    }

    // ---- stage: 42 rows x 20 aligned f4 groups, f16 in LDS --------------
    if (pair < 3) {
      const float* xb = vis  + (n*3 + pair)*CH_STRIDE;
      const float* yb = fuse + (n*3 + pair)*CH_STRIDE;
      for (int i = tid; i < SXH*20; i += 256) {
        int row = i / 20, k = i - row*20;
        int gy = y0 - 5 + row, gx = x0 - 8 + 4*k;
        f4 xv = {0,0,0,0}, yv = {0,0,0,0};
        if ((unsigned)gx < IMG_W && (unsigned)gy < IMG_H) {
          int off = gy*IMG_W + gx;
          xv = *(const f4*)&xb[off];
          yv = *(const f4*)&yb[off];
        }
        int ib = row*SXW + 4*k;
        *(h4*)&sx[ib] = h4{(_Float16)xv.x,(_Float16)xv.y,(_Float16)xv.z,(_Float16)xv.w};
        *(h4*)&sy[ib] = h4{(_Float16)yv.x,(_Float16)yv.y,(_Float16)yv.z,(_Float16)yv.w};
      }
    } else {
      const float* xb = ir   + n*IMG_STRIDE;
      const float* fb = fuse + n*IMG_STRIDE;
      for (int i = tid; i < SXH*20; i += 256) {
        int row = i / 20, k = i - row*20;
        int gy = y0 - 5 + row, gx = x0 - 8 + 4*k;
        f4 xv = {0,0,0,0}, yv = {0,0,0,0};
        if ((unsigned)gx < IMG_W && (unsigned)gy < IMG_H) {
          int off = gy*IMG_W + gx;
          xv = *(const f4*)&xb[off];
          f4 rr = *(const f4*)&fb[off];
          f4 gg = *(const f4*)&fb[off + CH_STRIDE];
          f4 bb = *(const f4*)&fb[off + 2*CH_STRIDE];
          #pragma unroll
          for (int j = 0; j < 4; ++j)
            yv[j] = 0.2989f*rr[j] + 0.587f*gg[j] + 0.114f*bb[j];
        }
        int ib = row*SXW + 4*k;
        *(h4*)&sx[ib] = h4{(_Float16)xv.x,(_Float16)xv.y,(_Float16)xv.z,(_Float16)xv.w};
        *(h4*)&sy[ib] = h4{(_Float16)yv.x,(_Float16)yv.y,(_Float16)yv.z,(_Float16)yv.w};
      }
    }
    __syncthreads();

    // ---- horizontal pass: 672 groups (42 rows x 16 x-groups) ------------
    for (int gi = tid; gi < SXH*16; gi += 256) {
      int row = gi >> 4, gox = (gi & 15)*4;
      int base = row*SXW + gox;
      float wa[20], wb[20];
      #pragma unroll
      for (int u = 0; u < 5; ++u) {
        h4 av = *(const h4*)&sx[base + 4*u];
        h4 bv = *(const h4*)&sy[base + 4*u];
        #pragma unroll
        for (int j = 0; j < 4; ++j) { wa[4*u+j] = (float)av[j]; wb[4*u+j] = (float)bv[j]; }
      }
      float wp[14], wq[14];
      #pragma unroll
      for (int u = 0; u < 14; ++u) {
        float a = wa[u+3], b = wb[u+3];
        wp[u] = fmaf(a, a, b*b);
        wq[u] = a*b;
      }
      float hA4[4]={0,0,0,0}, hB4[4]={0,0,0,0}, hP4[4]={0,0,0,0}, hQ4[4]={0,0,0,0};
      #pragma unroll
      for (int k = 0; k < 11; ++k) {
        float gk = g[k];
        #pragma unroll
        for (int j = 0; j < 4; ++j) {
          hA4[j] = fmaf(gk, wa[k+j+3], hA4[j]);
          hB4[j] = fmaf(gk, wb[k+j+3], hB4[j]);
          hP4[j] = fmaf(gk, wp[k+j], hP4[j]);
          hQ4[j] = fmaf(gk, wq[k+j], hQ4[j]);
        }
      }
      int ob = row*HBW + gox;
      *(h4*)&hA[ob] = h4{(_Float16)hA4[0],(_Float16)hA4[1],(_Float16)hA4[2],(_Float16)hA4[3]};
      *(h4*)&hB[ob] = h4{(_Float16)hB4[0],(_Float16)hB4[1],(_Float16)hB4[2],(_Float16)hB4[3]};
      *(h4*)&hP[ob] = h4{(_Float16)hP4[0],(_Float16)hP4[1],(_Float16)hP4[2],(_Float16)hP4[3]};
      *(h4*)&hQ[ob] = h4{(_Float16)hQ4[0],(_Float16)hQ4[1],(_Float16)hQ4[2],(_Float16)hQ4[3]};
    }
    __syncthreads();

    // ---- vertical pass: 256 strips of 4 wide x 2 rows -------------------
    const int vox = (tid & 15)*4;
    const int yb2 = (tid >> 4)*2;
    float aA0[4]={0,0,0,0}, aA1[4]={0,0,0,0};
    float aB0[4]={0,0,0,0}, aB1[4]={0,0,0,0};
    float aP0[4]={0,0,0,0}, aP1[4]={0,0,0,0};
    float aQ0[4]={0,0,0,0}, aQ1[4]={0,0,0,0};
    #pragma unroll
    for (int r = 0; r < 12; ++r) {
      int rb = (yb2 + r)*HBW + vox;
      h4 fA = *(const h4*)&hA[rb];
      h4 fB = *(const h4*)&hB[rb];
      h4 fP = *(const h4*)&hP[rb];
      h4 fQ = *(const h4*)&hQ[rb];
      if (r < 11) {
        float gk = g[r];
        #pragma unroll
        for (int j = 0; j < 4; ++j) {
          aA0[j] = fmaf(gk, (float)fA[j], aA0[j]);
          aB0[j] = fmaf(gk, (float)fB[j], aB0[j]);
          aP0[j] = fmaf(gk, (float)fP[j], aP0[j]);
          aQ0[j] = fmaf(gk, (float)fQ[j], aQ0[j]);
        }
      }
      if (r >= 1) {
        float gk = g[r-1];
        #pragma unroll
        for (int j = 0; j < 4; ++j) {
          aA1[j] = fmaf(gk, (float)fA[j], aA1[j]);
          aB1[j] = fmaf(gk, (float)fB[j], aB1[j]);
          aP1[j] = fmaf(gk, (float)fP[j], aP1[j]);
          aQ1[j] = fmaf(gk, (float)fQ[j], aQ1[j]);
        }
      }
    }

    float ss = 0.f;
    #pragma unroll
    for (int j = 0; j < 4; ++j) {
      {
        float mu1 = aA0[j], mu2 = aB0[j];
        float mu12 = mu1*mu2, mss = mu1*mu1 + mu2*mu2;
        float s12 = aQ0[j] - mu12, sps = aP0[j] - mss;
        ss += ((2.f*mu12 + 1e-4f)*(2.f*s12 + 9e-4f)) / ((mss + 1e-4f)*(sps + 9e-4f));
      }
      {
        float mu1 = aA1[j], mu2 = aB1[j];
        float mu12 = mu1*mu2, mss = mu1*mu1 + mu2*mu2;
        float s12 = aQ1[j] - mu12, sps = aP1[j] - mss;
        ss += ((2.f*mu12 + 1e-4f)*(2.f*s12 + 9e-4f)) / ((mss + 1e-4f)*(sps + 9e-4f));
      }
    }
    float tot = block_sum(ss, red);
    if (tid == 0) atomicAdd(&aslot[(pair == 3) ? 6 : 5], tot);

  } else {
    // ================= point + sobel + color block =================
    const int r = bid - 8192;
    const int x0 = (r & 7)*64;
    const int y0 = ((r >> 3) & 31)*16;
    const int n  = r >> 8;
    float* s = (float*)smem;   // 3 fields x 1224 floats (14.7 KB)
    const int ox = (tid & 15)*4;
    const int oy = tid >> 4;

    float con=0.f, gxs=0.f, gys=0.f, cbs=0.f, crs=0.f;
    float pv[3][4], pf[3][4];

    for (int c = 0; c < 3; ++c) {
      const float* pv0 = vis  + (n*3 + c)*CH_STRIDE;
      const float* pi0 = ir   + (n*3 + c)*CH_STRIDE;
      const float* pf0 = fuse + (n*3 + c)*CH_STRIDE;
      // interior: 3 fields x 18 rows x 16 f4 = 864 groups
      for (int i = tid; i < 864; i += 256) {
        int f = i / 288;
        int rr = i - f*288;
        int row = rr >> 4, k = rr & 15;
        int gy = y0 - 1 + row, gx = x0 + 4*k;   // gx always in-bounds
        f4 v = {0,0,0,0};
        const float* bp = (f == 0) ? pv0 : ((f == 1) ? pi0 : pf0);
        if ((unsigned)gy < IMG_H) v = *(const f4*)&bp[gy*IMG_W + gx];
        float* dst = s + f*R1N + row*R1W + 1 + 4*k;   // element m at idx m-x0+1
        dst[0]=v.x; dst[1]=v.y; dst[2]=v.z; dst[3]=v.w;
      }
      // edges: 3 fields x 18 rows x 2 = 108 scalars
      if (tid < 108) {
        int f = tid / 36;
        int rr = tid - f*36;
        int row = rr >> 1, side = rr & 1;
        int gy = y0 - 1 + row;
        int gx = side ? (x0 + 64) : (x0 - 1);
        float v = 0.f;
        const float* bp = (f == 0) ? pv0 : ((f == 1) ? pi0 : pf0);
        if ((unsigned)gx < IMG_W && (unsigned)gy < IMG_H) v = bp[gy*IMG_W + gx];
        s[f*R1N + row*R1W + (side ? 65 : 0)] = v;
      }
      __syncthreads();

      float cen[3][4], gxv[3][4], gyv[3][4];
      #pragma unroll
      for (int t = 0; t < 3; ++t) {
        const float* sf = s + t*R1N;
        float r0[8], r1[8], r2[8];
        {
          f4 a = *(const f4*)&sf[(oy+0)*R1W + ox], b = *(const f4*)&sf[(oy+0)*R1W + ox + 4];
          r0[0]=a.x; r0[1]=a.y; r0[2]=a.z; r0[3]=a.w; r0[4]=b.x; r0[5]=b.y; r0[6]=b.z; r0[7]=b.w;
        }
        {
          f4 a = *(const f4*)&sf[(oy+1)*R1W + ox], b = *(const f4*)&sf[(oy+1)*R1W + ox + 4];
          r1[0]=a.x; r1[1]=a.y; r1[2]=a.z; r1[3]=a.w; r1[4]=b.x; r1[5]=b.y; r1[6]=b.z; r1[7]=b.w;
        }
        {
          f4 a = *(const f4*)&sf[(oy+2)*R1W + ox], b = *(const f4*)&sf[(oy+2)*R1W + ox + 4];
          r2[0]=a.x; r2[1]=a.y; r2[2]=a.z; r2[3]=a.w; r2[4]=b.x; r2[5]=b.y; r2[6]=b.z; r2[7]=b.w;
        }
        #pragma unroll
        for (int j = 0; j < 4; ++j) {
          gxv[t][j] = (r0[j+2]-r0[j]) + 2.f*(r1[j+2]-r1[j]) + (r2[j+2]-r2[j]);
          gyv[t][j] = (r0[j] + 2.f*r0[j+1] + r0[j+2]) - (r2[j] + 2.f*r2[j+1] + r2[j+2]);
          cen[t][j] = r1[j+1];
        }
      }
      #pragma unroll
      for (int j = 0; j < 4; ++j) {
        con += fabsf(cen[2][j] - fmaxf(cen[0][j], cen[1][j]));
        gxs += fabsf(gxv[2][j] - fmaxf(gxv[0][j], gxv[1][j]));
        gys += fabsf(gyv[2][j] - fmaxf(gyv[0][j], gyv[1][j]));
        pv[c][j] = cen[0][j];
        pf[c][j] = cen[2][j];
      }
      __syncthreads();   // WAR guard before restaging
    }

    #pragma unroll
    for (int j = 0; j < 4; ++j) {
      float Yf = 0.299f*pf[0][j] + 0.587f*pf[1][j] + 0.114f*pf[2][j];
      float Yv = 0.299f*pv[0][j] + 0.587f*pv[1][j] + 0.114f*pv[2][j];
      crs += fabsf(0.713f*((pf[0][j]-Yf) - (pv[0][j]-Yv)));
      cbs += fabsf(0.564f*((pf[2][j]-Yf) - (pv[2][j]-Yv)));
    }

    float r0 = block_sum(con, red);
    float r1 = block_sum(gxs, red);
    float r2 = block_sum(gys, red);
    float r3 = block_sum(cbs, red);
    float r4 = block_sum(crs, red);
    if (tid == 0) {
      atomicAdd(&aslot[0], r0);
      atomicAdd(&aslot[1], r1);
      atomicAdd(&aslot[2], r2);
      atomicAdd(&aslot[3], r3);
      atomicAdd(&aslot[4], r4);
    }
  }
}

// ---------------- final combine: one wave over 64 slots -------------------
__global__ __launch_bounds__(64) void k_final(
    const float* __restrict__ acc, float* __restrict__ out)
{
  int lane = threadIdx.x;
  float s[7];
  #pragma unroll
  for (int c = 0; c < 7; ++c) {
    float x = acc[lane*SLOT_F + c];
    #pragma unroll
    for (int o = 32; o > 0; o >>= 1) x += __shfl_down(x, o, 64);
    s[c] = x;
  }
  if (lane == 0) {
    const float N3 = 16.f*3.f*512.f*512.f;
    const float N1 = 16.f*512.f*512.f;
    float con_loss  = s[0] / N3;
    float grad_loss = 0.5f*(s[1]/N3) + 0.5f*(s[2]/N3);
    float color_loss = s[3]/N1 + s[4]/N1;
    float ssim_loss = 1.f - (s[5]/N3 + s[6]/N1)*0.5f;
    out[0] = 0.5f*con_loss + 0.2f*grad_loss + color_loss + 0.1f*ssim_loss;
  }
}

extern "C" void kernel_launch(void* const* d_in, const int* in_sizes, int n_in,
                              void* d_out, int out_size, void* d_ws, size_t ws_size,
                              hipStream_t stream) {
  (void)in_sizes; (void)n_in; (void)out_size; (void)ws_size;
  const float* vis  = (const float*)d_in[0];
  const float* ir   = (const float*)d_in[1];
  const float* fuse = (const float*)d_in[2];
  float* out = (float*)d_out;
  float* acc = (float*)d_ws;   // 64 slots x 32 floats = 8 KB

  k_zero<<<dim3(1,1,1), dim3(256,1,1), 0, stream>>>(acc);
  k_main<<<dim3(12288,1,1), dim3(256,1,1), 0, stream>>>(vis, ir, fuse, acc);
  k_final<<<dim3(1,1,1), dim3(64,1,1), 0, stream>>>(acc, out);
}